// Round 11
// baseline (340.141 us; speedup 1.0000x reference)
//
#include <hip/hip_runtime.h>

#define N_NODES 100000
#define N_EDGES 600000
#define N_GRAPHS 64

// ---------------- CSR build ----------------

__global__ void k_count(const int* __restrict__ dst, int* __restrict__ deg) {
    int e = blockIdx.x * 256 + threadIdx.x;
    if (e < N_EDGES) atomicAdd(&deg[dst[e]], 1);
}

__global__ void k_scan1(const int* __restrict__ deg, int* __restrict__ offs,
                        int* __restrict__ bsums) {
    __shared__ int s[256];
    int t = threadIdx.x, b = blockIdx.x;
    int base = b * 1024 + t * 4;
    int v0 = (base + 0 < N_NODES) ? deg[base + 0] : 0;
    int v1 = (base + 1 < N_NODES) ? deg[base + 1] : 0;
    int v2 = (base + 2 < N_NODES) ? deg[base + 2] : 0;
    int v3 = (base + 3 < N_NODES) ? deg[base + 3] : 0;
    int tsum = v0 + v1 + v2 + v3;
    s[t] = tsum;
    __syncthreads();
    for (int o = 1; o < 256; o <<= 1) {
        int x = (t >= o) ? s[t - o] : 0;
        __syncthreads();
        s[t] += x;
        __syncthreads();
    }
    int p = s[t] - tsum;
    if (base + 0 < N_NODES) offs[base + 0] = p;
    p += v0;
    if (base + 1 < N_NODES) offs[base + 1] = p;
    p += v1;
    if (base + 2 < N_NODES) offs[base + 2] = p;
    p += v2;
    if (base + 3 < N_NODES) offs[base + 3] = p;
    if (t == 255) bsums[b] = s[255];
}

__global__ void k_scan2(const int* __restrict__ bsums, int* __restrict__ boff) {
    __shared__ int s[128];
    int t = threadIdx.x;
    int nb = (N_NODES + 1023) / 1024;
    int v = (t < nb) ? bsums[t] : 0;
    s[t] = v;
    __syncthreads();
    for (int o = 1; o < 128; o <<= 1) {
        int x = (t >= o) ? s[t - o] : 0;
        __syncthreads();
        s[t] += x;
        __syncthreads();
    }
    boff[t] = s[t] - v;
}

__global__ void k_scan3(int* __restrict__ offs, const int* __restrict__ boff,
                        int* __restrict__ cursor) {
    int i = blockIdx.x * 256 + threadIdx.x;
    if (i < N_NODES) {
        int v = offs[i] + boff[i >> 10];
        offs[i] = v;
        cursor[i] = v;
    }
}

__global__ void k_fill(const int* __restrict__ src, const int* __restrict__ dst,
                       int* __restrict__ cursor, int* __restrict__ ssrc) {
    int e = blockIdx.x * 256 + threadIdx.x;
    if (e < N_EDGES) {
        int d = dst[e];
        int pos = atomicAdd(&cursor[d], 1);
        ssrc[pos] = src[e];
    }
}

// ---------------- weight prepack ----------------
// Pg[k*128 + d]: d<64 -> W1l[d][k], d>=64 -> W1r[d-64][k]   (xform1 B matrix)
// P2g[k*32 + d]: d<16 -> W2l[d][k], d>=16 -> W2r[d-16][k]   (xform2, s_load rows)
__global__ void k_prepack(const float* __restrict__ W1l, const float* __restrict__ W1r,
                          const float* __restrict__ W2l, const float* __restrict__ W2r,
                          float* __restrict__ Pg, float* __restrict__ P2g) {
    int i = blockIdx.x * 256 + threadIdx.x;
    if (i < 16384) {
        int k = i >> 7, d = i & 127;
        Pg[i] = (d < 64) ? W1l[d * 128 + k] : W1r[(d - 64) * 128 + k];
    } else if (i < 18432) {
        int j = i - 16384, k = j >> 5, d = j & 31;
        P2g[j] = (d < 16) ? W2l[d * 64 + k] : W2r[(d - 16) * 64 + k];
    }
}

// ---------------- xform1: register-blocked fp32 GEMM (R6 structure, best known) ----
// C[128 nodes x 128 dims] per block; dims 0..63 -> xl, 64..127 -> xr (h1 buf).
// 4 waves in 2x2; lane owns 8x8 micro-tile; A,B staged in LDS (padded stride).

#define KC 32
#define LDP 132  // LDS row stride in floats (528 B, 16B-aligned)

__launch_bounds__(256, 4)
__global__ void k_xform1(const float* __restrict__ x, const float* __restrict__ Pg,
                         float* __restrict__ xl, float* __restrict__ xr) {
    __shared__ float At[KC * LDP];  // At[kk][n]  n<128  (x tile, transposed)
    __shared__ float Bt[KC * LDP];  // Bt[kk][d]  d<128  (weights)
    int tid = threadIdx.x;
    int wave = tid >> 6, lane = tid & 63;
    int wr = wave >> 1, wc = wave & 1;
    int li = lane >> 3, lj = lane & 7;
    int tbase = blockIdx.x * 128;
    const float4* x4 = (const float4*)x;
    const float4* Pg4 = (const float4*)Pg;

    float acc[8][8];
#pragma unroll
    for (int i = 0; i < 8; ++i)
#pragma unroll
        for (int j = 0; j < 8; ++j) acc[i][j] = 0.f;

    for (int k0 = 0; k0 < 128; k0 += KC) {
        if (k0) __syncthreads();
        // stage A: idx = n*8+q -> x[tbase+n][k0+4q..+3], stored transposed
#pragma unroll
        for (int u = 0; u < 4; ++u) {
            int idx = u * 256 + tid;
            int n = idx >> 3, q = idx & 7;
            int node = min(tbase + n, N_NODES - 1);
            float4 v = x4[node * 32 + (k0 >> 2) + q];
            At[(4 * q + 0) * LDP + n] = v.x;
            At[(4 * q + 1) * LDP + n] = v.y;
            At[(4 * q + 2) * LDP + n] = v.z;
            At[(4 * q + 3) * LDP + n] = v.w;
        }
        // stage B: idx = kk*32+q -> Pg[(k0+kk)*128 + 4q..+3]
#pragma unroll
        for (int u = 0; u < 4; ++u) {
            int idx = u * 256 + tid;
            int kk = idx >> 5, q = idx & 31;
            float4 w = Pg4[(k0 + kk) * 32 + q];
            *(float4*)&Bt[kk * LDP + 4 * q] = w;
        }
        __syncthreads();
#pragma unroll 4
        for (int kk = 0; kk < KC; ++kk) {
            float a[8], b[8];
            *(float4*)&a[0] = *(const float4*)&At[kk * LDP + wr * 64 + li * 8];
            *(float4*)&a[4] = *(const float4*)&At[kk * LDP + wr * 64 + li * 8 + 4];
            *(float4*)&b[0] = *(const float4*)&Bt[kk * LDP + wc * 64 + lj * 8];
            *(float4*)&b[4] = *(const float4*)&Bt[kk * LDP + wc * 64 + lj * 8 + 4];
#pragma unroll
            for (int i = 0; i < 8; ++i)
#pragma unroll
                for (int j = 0; j < 8; ++j)
                    acc[i][j] = fmaf(a[i], b[j], acc[i][j]);
        }
    }
    // epilogue: wc==0 -> xl, wc==1 -> xr; dims lj*8..lj*8+7 within the buffer
    float* outb = wc ? xr : xl;
#pragma unroll
    for (int i = 0; i < 8; ++i) {
        int node = tbase + wr * 64 + li * 8 + i;
        if (node < N_NODES) {
            float4* p = (float4*)(outb + node * 64 + lj * 8);
            p[0] = make_float4(acc[i][0], acc[i][1], acc[i][2], acc[i][3]);
            p[1] = make_float4(acc[i][4], acc[i][5], acc[i][6], acc[i][7]);
        }
    }
}

// ---------------- gather1 v3: wide gather --------------------------------------
// lane = (sub, q): sub = neighbor slot (4), q = float4 slot (16).
// One load instruction fetches 4 whole 256B rows; 2 per iteration (8 neighbors).
// shfl_xor(16,32) reduces across subs; quarter-wave float4 store.

__launch_bounds__(256)
__global__ void k_gather1(const float* __restrict__ xl, const int* __restrict__ ssrc,
                          const int* __restrict__ offs, const int* __restrict__ deg,
                          const float* __restrict__ b1, float* __restrict__ h1) {
    int tid = blockIdx.x * 256 + threadIdx.x;
    int wid = tid >> 6, lane = tid & 63;
    int nWaves = (gridDim.x * 256) >> 6;
    int sub = lane >> 4, q = lane & 15;
    float4 bias = ((const float4*)b1)[q];
    const float4* xl4 = (const float4*)xl;
    float4* h14 = (float4*)h1;

    int node = wid;
    if (node >= N_NODES) return;
    int o = offs[node], dg = deg[node];
    float4 self = h14[node * 16 + q];
    while (true) {
        // prefetch next node's metadata + self row (hides under gather)
        int nnode = node + nWaves;
        int no = 0, ndg = 0;
        float4 nself = make_float4(0.f, 0.f, 0.f, 0.f);
        if (nnode < N_NODES) {
            no = offs[nnode];
            ndg = deg[nnode];
            nself = h14[nnode * 16 + q];
        }
        int os = __builtin_amdgcn_readfirstlane(o);
        int ds = __builtin_amdgcn_readfirstlane(dg);
        float ax = 0.f, ay = 0.f, az = 0.f, aw = 0.f;
        int last = ds - 1;  // loop only entered when ds >= 1
        for (int u = 0; u < ds; u += 8) {
            int na = ssrc[os + min(u + sub, last)];       // pad re-reads last row (L1 hit)
            int nb = ssrc[os + min(u + 4 + sub, last)];
            float4 va = xl4[na * 16 + q];
            float4 vb = xl4[nb * 16 + q];
            float ma = (u + sub < ds) ? 1.f : 0.f;
            float mb = (u + 4 + sub < ds) ? 1.f : 0.f;
            ax = fmaf(va.x, ma, ax); ay = fmaf(va.y, ma, ay);
            az = fmaf(va.z, ma, az); aw = fmaf(va.w, ma, aw);
            ax = fmaf(vb.x, mb, ax); ay = fmaf(vb.y, mb, ay);
            az = fmaf(vb.z, mb, az); aw = fmaf(vb.w, mb, aw);
        }
        // reduce across the 4 sub groups (lane bits 4,5)
        ax += __shfl_xor(ax, 16); ay += __shfl_xor(ay, 16);
        az += __shfl_xor(az, 16); aw += __shfl_xor(aw, 16);
        ax += __shfl_xor(ax, 32); ay += __shfl_xor(ay, 32);
        az += __shfl_xor(az, 32); aw += __shfl_xor(aw, 32);
        float inv = 1.f / (float)max(ds, 1);
        if (sub == 0) {
            float4 r;
            r.x = fmaxf(self.x + bias.x + ax * inv, 0.f);
            r.y = fmaxf(self.y + bias.y + ay * inv, 0.f);
            r.z = fmaxf(self.z + bias.z + az * inv, 0.f);
            r.w = fmaxf(self.w + bias.w + aw * inv, 0.f);
            h14[node * 16 + q] = r;
        }
        if (nnode >= N_NODES) break;
        node = nnode;
        o = no;
        dg = ndg;
        self = nself;
    }
}

// ---------------- xform2: lane = node, scalar weights (8 FMA / s_load float) -------

#define LD2 68

__launch_bounds__(256)
__global__ void k_xform2(const float* __restrict__ h1, const float* __restrict__ P2g,
                         float* __restrict__ h1l, float* __restrict__ h2pre) {
    __shared__ float S[64 * LD2];  // 17.4 KB
    int tid = threadIdx.x;
    int wave = __builtin_amdgcn_readfirstlane(tid >> 6);
    int lane = tid & 63;
    int tbase = blockIdx.x * 64;
    const float4* h4 = (const float4*)h1;

    for (int idx = tid; idx < 64 * 16; idx += 256) {
        int n = idx >> 4, q = idx & 15;
        int node = min(tbase + n, N_NODES - 1);
        *(float4*)&S[n * LD2 + 4 * q] = h4[node * 16 + q];
    }
    __syncthreads();

    int node = tbase + lane;
    int dbase = wave * 8;
    float acc[8] = {0.f, 0.f, 0.f, 0.f, 0.f, 0.f, 0.f, 0.f};
    const float* Sn = S + lane * LD2;
#pragma unroll 4
    for (int k4 = 0; k4 < 16; ++k4) {
        float4 s = *(const float4*)&Sn[4 * k4];
        const float* Wk = P2g + (4 * k4) * 32 + dbase;
#pragma unroll
        for (int c = 0; c < 4; ++c) {
            float sv = (c == 0) ? s.x : (c == 1) ? s.y : (c == 2) ? s.z : s.w;
            const float* W = Wk + c * 32;
#pragma unroll
            for (int dd = 0; dd < 8; ++dd)
                acc[dd] = fmaf(W[dd], sv, acc[dd]);
        }
    }
    if (node < N_NODES) {
        float4 lo = make_float4(acc[0], acc[1], acc[2], acc[3]);
        float4 hi = make_float4(acc[4], acc[5], acc[6], acc[7]);
        if (wave < 2) {
            float4* p = (float4*)(h1l + node * 16 + wave * 8);
            p[0] = lo;
            p[1] = hi;
        } else {
            float4* p = (float4*)(h2pre + node * 16 + (wave - 2) * 8);
            p[0] = lo;
            p[1] = hi;
        }
    }
}

// ---------------- g2pool v3: wave-per-node wide gather + pooling -------------------
// lane = (slot, d4): slot = neighbor slot (16), d4 = float4 slot (4).
// One load fetches 16 rows (64B each); deg<=16 in one shot. xor-reduce bits 2..5.

__launch_bounds__(256)
__global__ void k_g2pool(const float* __restrict__ h1l, const float* __restrict__ h2pre,
                         const int* __restrict__ ssrc, const int* __restrict__ offs,
                         const int* __restrict__ deg, const int* __restrict__ batch,
                         const float* __restrict__ b2,
                         float* __restrict__ gsum, float* __restrict__ gcnt) {
    __shared__ float bins[N_GRAPHS][17];
    int tid = threadIdx.x;
    for (int i = tid; i < N_GRAPHS * 17; i += 256) ((float*)bins)[i] = 0.f;
    __syncthreads();

    int wave = tid >> 6, lane = tid & 63;
    int slot = lane >> 2, d4 = lane & 3;
    float4 bias = ((const float4*)b2)[d4];
    const float4* hl4 = (const float4*)h1l;
    const float4* hp4 = (const float4*)h2pre;

    int chunk = (N_NODES + gridDim.x - 1) / gridDim.x;
    int cs = blockIdx.x * chunk;
    int ce = min(N_NODES, cs + chunk);

    for (int node = cs + wave; node < ce; node += 4) {
        int os = __builtin_amdgcn_readfirstlane(offs[node]);
        int ds = __builtin_amdgcn_readfirstlane(deg[node]);
        float4 hp = hp4[node * 4 + d4];
        float ax = 0.f, ay = 0.f, az = 0.f, aw = 0.f;
        int last = ds - 1;
        for (int u = 0; u < ds; u += 16) {
            int n = ssrc[os + min(u + slot, last)];
            float4 v = hl4[n * 4 + d4];
            float m = (u + slot < ds) ? 1.f : 0.f;
            ax = fmaf(v.x, m, ax); ay = fmaf(v.y, m, ay);
            az = fmaf(v.z, m, az); aw = fmaf(v.w, m, aw);
        }
        // reduce across 16 slots (lane bits 2..5)
#pragma unroll
        for (int off = 4; off <= 32; off <<= 1) {
            ax += __shfl_xor(ax, off); ay += __shfl_xor(ay, off);
            az += __shfl_xor(az, off); aw += __shfl_xor(aw, off);
        }
        float inv = 1.f / (float)max(ds, 1);
        float4 val;
        val.x = hp.x + bias.x + ax * inv;
        val.y = hp.y + bias.y + ay * inv;
        val.z = hp.z + bias.z + az * inv;
        val.w = hp.w + bias.w + aw * inv;
        int g = batch[node];
        if (lane < 4) {
            atomicAdd(&bins[g][4 * lane + 0], val.x);
            atomicAdd(&bins[g][4 * lane + 1], val.y);
            atomicAdd(&bins[g][4 * lane + 2], val.z);
            atomicAdd(&bins[g][4 * lane + 3], val.w);
        }
        if (lane == 0) atomicAdd(&bins[g][16], 1.f);
    }
    __syncthreads();
    for (int i = tid; i < N_GRAPHS * 17; i += 256) {
        int g = i / 17, c = i - g * 17;
        float v = bins[g][c];
        if (v != 0.f) {
            if (c < 16) atomicAdd(&gsum[g * 16 + c], v);
            else        atomicAdd(&gcnt[g], v);
        }
    }
}

// ---------------- final: BERT head + graph head, concat ----------------

__global__ void k_final(const float* __restrict__ bert, const float* __restrict__ Wad,
                        const float* __restrict__ bad, const float* __restrict__ Wm,
                        const float* __restrict__ bm, const float* __restrict__ gsum,
                        const float* __restrict__ gcnt, float* __restrict__ out) {
    int g = blockIdx.x;
    int t = threadIdx.x;
    if (t < 64) {
        const float4* br = (const float4*)(bert + g * 768);
        const float4* wr = (const float4*)(Wad + t * 768);
        float acc = bad[t];
#pragma unroll 8
        for (int k = 0; k < 192; ++k) {
            float4 bv = br[k], wv = wr[k];
            acc += bv.x * wv.x + bv.y * wv.y + bv.z * wv.z + bv.w * wv.w;
        }
        out[g * 80 + t] = acc;
    } else if (t < 80) {
        int j = t - 64;
        float ic = 1.f / fmaxf(gcnt[g], 1.f);
        float acc = bm[j];
#pragma unroll
        for (int k = 0; k < 16; ++k) acc += Wm[j * 16 + k] * gsum[g * 16 + k] * ic;
        out[g * 80 + t] = acc;
    }
}

extern "C" void kernel_launch(void* const* d_in, const int* in_sizes, int n_in,
                              void* d_out, int out_size, void* d_ws, size_t ws_size,
                              hipStream_t stream) {
    const float* bert   = (const float*)d_in[0];
    const float* node_x = (const float*)d_in[1];
    const int*   edge   = (const int*)d_in[2];
    const int*   batch  = (const int*)d_in[3];
    const float* Wad    = (const float*)d_in[4];
    const float* bad    = (const float*)d_in[5];
    const float* W1l    = (const float*)d_in[6];
    const float* W1r    = (const float*)d_in[7];
    const float* b1     = (const float*)d_in[8];
    const float* W2l    = (const float*)d_in[9];
    const float* W2r    = (const float*)d_in[10];
    const float* b2     = (const float*)d_in[11];
    const float* Wm     = (const float*)d_in[12];
    const float* bm     = (const float*)d_in[13];
    float* out = (float*)d_out;

    const int* src = edge;
    const int* dst = edge + N_EDGES;

    char* ws = (char*)d_ws;
    int*    deg    = (int*)(ws);                //   400,000 B
    int*    offs   = (int*)(ws + 400000);       //   400,000 B
    int*    cursor = (int*)(ws + 800000);       //   400,000 B
    int*    bsums  = (int*)(ws + 1200000);      //       512 B
    int*    boff   = (int*)(ws + 1200512);      //       512 B
    int*    ssrc   = (int*)(ws + 1201024);      // 2,400,000 B
    float*  xl     = (float*)(ws + 3601024);    // 25,600,000 B
    float*  h1     = (float*)(ws + 29201024);   // 25,600,000 B  (xr, then h1 in-place)
    float*  Pg     = (float*)(ws + 54801024);   //    65,536 B
    float*  P2g    = (float*)(ws + 54866560);   //     8,192 B
    float*  gsum   = (float*)(ws + 54874752);   //     4,096 B
    float*  gcnt   = (float*)(ws + 54878848);   //       256 B
    // layer-2 buffers alias dead xl region:
    float*  h1l    = (float*)(ws + 3601024);    //  6,400,000 B
    float*  h2pre  = (float*)(ws + 10001024);   //  6,400,000 B
    // peak ~54.9 MB

    hipMemsetAsync(deg, 0, 400000, stream);
    hipMemsetAsync(gsum, 0, 4096 + 256, stream);

    k_count<<<(N_EDGES + 255) / 256, 256, 0, stream>>>(dst, deg);
    k_scan1<<<(N_NODES + 1023) / 1024, 256, 0, stream>>>(deg, offs, bsums);
    k_scan2<<<1, 128, 0, stream>>>(bsums, boff);
    k_scan3<<<(N_NODES + 255) / 256, 256, 0, stream>>>(offs, boff, cursor);
    k_fill<<<(N_EDGES + 255) / 256, 256, 0, stream>>>(src, dst, cursor, ssrc);
    k_prepack<<<72, 256, 0, stream>>>(W1l, W1r, W2l, W2r, Pg, P2g);

    int nT128 = (N_NODES + 127) / 128;  // 782
    int nT64  = (N_NODES + 63) / 64;    // 1563
    k_xform1<<<nT128, 256, 0, stream>>>(node_x, Pg, xl, h1);
    k_gather1<<<2048, 256, 0, stream>>>(xl, ssrc, offs, deg, b1, h1);
    k_xform2<<<nT64, 256, 0, stream>>>(h1, P2g, h1l, h2pre);
    k_g2pool<<<512, 256, 0, stream>>>(h1l, h2pre, ssrc, offs, deg, batch, b2, gsum, gcnt);
    k_final<<<N_GRAPHS, 128, 0, stream>>>(bert, Wad, bad, Wm, bm, gsum, gcnt, out);
}